// Round 1
// baseline (787.668 us; speedup 1.0000x reference)
//
#include <hip/hip_runtime.h>
#include <cstdint>
#include <cstddef>

#define AS1 __attribute__((address_space(1)))
#define AS3 __attribute__((address_space(3)))

typedef __attribute__((ext_vector_type(4))) float f32x4;

constexpr int HD = 4096;   // hidden dim (= K = out dim)
constexpr float FP8MAX = 448.0f;

// ---------------- reductions ----------------
__device__ inline float wave_red(float v, bool ismax) {
#pragma unroll
    for (int i = 32; i > 0; i >>= 1) {
        float o = __shfl_xor(v, i, 64);
        v = ismax ? fmaxf(v, o) : (v + o);
    }
    return v;
}

__device__ inline float blk_red(float v, float* red, bool ismax) {
    v = wave_red(v, ismax);
    const int wid = threadIdx.x >> 6;
    __syncthreads();                      // protect red from previous use
    if ((threadIdx.x & 63) == 0) red[wid] = v;
    __syncthreads();
    float a = red[0], b = red[1], c = red[2], d = red[3];
    return ismax ? fmaxf(fmaxf(a, b), fmaxf(c, d)) : ((a + b) + (c + d));
}

// ---------------- fp8 pack ----------------
__device__ inline uint32_t pack4_fp8(float a, float b, float c, float d) {
    int v = 0;
    v = __builtin_amdgcn_cvt_pk_fp8_f32(a, b, v, false);  // low word
    v = __builtin_amdgcn_cvt_pk_fp8_f32(c, d, v, true);   // high word
    return (uint32_t)v;
}

__device__ inline float clipdiv(float y, float s) {
    float t = y / s;                       // IEEE div to match numpy exactly
    t = fminf(t, FP8MAX);
    t = fmaxf(t, -FP8MAX);
    return t;
}

// ---------------- weight absmax (per tensor, blockIdx.z selects W) ----------------
__global__ __launch_bounds__(256) void w_absmax(const float* __restrict__ W0,
                                                const float* __restrict__ W1,
                                                const float* __restrict__ W2,
                                                uint32_t* __restrict__ wmax) {
    __shared__ float red[4];
    const float* W = (blockIdx.z == 0) ? W0 : (blockIdx.z == 1 ? W1 : W2);
    const float4* W4 = (const float4*)W;
    const int n4 = HD * HD / 4;
    float m = 0.f;
    for (int i = blockIdx.x * blockDim.x + threadIdx.x; i < n4; i += gridDim.x * blockDim.x) {
        float4 v = W4[i];
        m = fmaxf(m, fmaxf(fmaxf(fabsf(v.x), fabsf(v.y)), fmaxf(fabsf(v.z), fabsf(v.w))));
    }
    m = blk_red(m, red, true);
    if (threadIdx.x == 0)
        atomicMax((unsigned int*)(wmax + blockIdx.z), __float_as_uint(m));
}

// ---------------- weight quantize ----------------
__global__ __launch_bounds__(256) void w_quant(const float* __restrict__ W,
                                               const uint32_t* __restrict__ wmaxbits,
                                               uint32_t* __restrict__ qw) {
    const float sw = fmaxf(__uint_as_float(*wmaxbits) / FP8MAX, 1e-12f);
    const int i = blockIdx.x * blockDim.x + threadIdx.x;
    float4 v = ((const float4*)W)[i];
    qw[i] = pack4_fp8(clipdiv(v.x, sw), clipdiv(v.y, sw), clipdiv(v.z, sw), clipdiv(v.w, sw));
}

// ---------------- fused (relu|add) + rmsnorm + (quant | final write) ----------------
// mode 0: v = relu(xin); store resid; quant
// mode 1: v = xin + addin; store resid; quant
// mode 2: v = xin + addin; write y to yout (final), no resid/quant
__global__ __launch_bounds__(256) void fused_rms(const float* __restrict__ xin,
                                                 const float* __restrict__ addin,
                                                 float* __restrict__ resid_out,
                                                 const float* __restrict__ nw,
                                                 uint32_t* __restrict__ qx,
                                                 float* __restrict__ srow,
                                                 float* __restrict__ yout,
                                                 const int mode) {
    __shared__ float red[4];
    const int row = blockIdx.x;
    const int tid = threadIdx.x;
    const size_t base = (size_t)row * HD;
    const float4* xr = (const float4*)(xin + base);

    float4 v[4];
    float ss = 0.f;
    if (mode == 0) {
#pragma unroll
        for (int j = 0; j < 4; j++) {
            float4 t = xr[tid + j * 256];
            t.x = fmaxf(t.x, 0.f); t.y = fmaxf(t.y, 0.f);
            t.z = fmaxf(t.z, 0.f); t.w = fmaxf(t.w, 0.f);
            v[j] = t;
            ss += t.x * t.x + t.y * t.y + t.z * t.z + t.w * t.w;
        }
    } else {
        const float4* ar = (const float4*)(addin + base);
#pragma unroll
        for (int j = 0; j < 4; j++) {
            float4 t = xr[tid + j * 256];
            float4 a = ar[tid + j * 256];
            t.x += a.x; t.y += a.y; t.z += a.z; t.w += a.w;
            v[j] = t;
            ss += t.x * t.x + t.y * t.y + t.z * t.z + t.w * t.w;
        }
    }
    if (resid_out) {
        float4* ro = (float4*)(resid_out + base);
#pragma unroll
        for (int j = 0; j < 4; j++) ro[tid + j * 256] = v[j];
    }
    ss = blk_red(ss, red, false);
    const float rs = 1.0f / sqrtf(ss / (float)HD + 1e-6f);

    const float4* nw4 = (const float4*)nw;
    float4 y[4];
    float amax = 0.f;
#pragma unroll
    for (int j = 0; j < 4; j++) {
        float4 w = nw4[tid + j * 256];
        float4 t;
        t.x = (v[j].x * rs) * w.x; t.y = (v[j].y * rs) * w.y;
        t.z = (v[j].z * rs) * w.z; t.w = (v[j].w * rs) * w.w;
        y[j] = t;
        amax = fmaxf(amax, fmaxf(fmaxf(fabsf(t.x), fabsf(t.y)), fmaxf(fabsf(t.z), fabsf(t.w))));
    }

    if (mode == 2) {
        float4* yo = (float4*)(yout + base);
#pragma unroll
        for (int j = 0; j < 4; j++) yo[tid + j * 256] = y[j];
        return;
    }

    amax = blk_red(amax, red, true);
    const float s = fmaxf(amax / FP8MAX, 1e-12f);
    if (tid == 0) srow[row] = s;
    uint32_t* qr = qx + base / 4;
#pragma unroll
    for (int j = 0; j < 4; j++) {
        qr[tid + j * 256] = pack4_fp8(clipdiv(y[j].x, s), clipdiv(y[j].y, s),
                                      clipdiv(y[j].z, s), clipdiv(y[j].w, s));
    }
}

// ---------------- fp8 GEMM: out[m][n] = (sum_k qx[m][k]*qw[n][k]) * srow[m] * ws ----------------
// 128x128 tile, BK=64, 4 waves in 2x2, each wave 4x4 tiles of 16x16x32 MFMA.
// LDS: [128 rows][64B], 16B groups XOR-swizzled by ((row>>1)&3) so ds_read_b64
// fragment reads are only 2-way bank-aliased (free). global_load_lds width=16.
__global__ __launch_bounds__(256) void gemm_fp8(const uint8_t* __restrict__ qx,
                                                const uint8_t* __restrict__ qw,
                                                const float* __restrict__ srow,
                                                const uint32_t* __restrict__ wmaxbits,
                                                float* __restrict__ out) {
    __shared__ uint8_t As[128 * 64];
    __shared__ uint8_t Bs[128 * 64];

    const int tid = threadIdx.x;
    const int wave = tid >> 6;
    const int lane = tid & 63;
    const int q = lane >> 4;   // 0..3
    const int r = lane & 15;

    const int m0 = blockIdx.y * 128;
    const int n0 = blockIdx.x * 128;
    const int wm = (wave >> 1) * 64;
    const int wn = (wave & 1) * 64;

    const f32x4 z4 = {0.f, 0.f, 0.f, 0.f};
    f32x4 acc[4][4];
#pragma unroll
    for (int i = 0; i < 4; i++)
#pragma unroll
        for (int j = 0; j < 4; j++) acc[i][j] = z4;

    // staging: wave handles rows [wave*32, wave*32+32) of each tile, 2 chunks of 16 rows.
    // physical slot for lane l in chunk: row = base+l/4, 16B-group = l&3;
    // global source group = (l&3) ^ ((row>>1)&3)  (the swizzle).
    const uint8_t* ag[2];
    const uint8_t* bg[2];
    int lbase[2];
#pragma unroll
    for (int c = 0; c < 2; c++) {
        int row = wave * 32 + c * 16 + (lane >> 2);
        int lg = (lane & 3) ^ ((row >> 1) & 3);
        lbase[c] = (wave * 32 + c * 16) * 64;
        ag[c] = qx + (size_t)(m0 + row) * HD + lg * 16;
        bg[c] = qw + (size_t)(n0 + row) * HD + lg * 16;
    }

    for (int k0 = 0; k0 < HD; k0 += 64) {
#pragma unroll
        for (int c = 0; c < 2; c++) {
            __builtin_amdgcn_global_load_lds((const AS1 void*)(ag[c] + k0),
                                             (AS3 void*)(As + lbase[c]), 16, 0, 0);
            __builtin_amdgcn_global_load_lds((const AS1 void*)(bg[c] + k0),
                                             (AS3 void*)(Bs + lbase[c]), 16, 0, 0);
        }
        __syncthreads();

#pragma unroll
        for (int ks = 0; ks < 2; ks++) {
            long af[4], bf[4];
#pragma unroll
            for (int i = 0; i < 4; i++) {
                int arow = wm + i * 16 + r;
                af[i] = *(const long*)(As + arow * 64 +
                        ((((ks << 1) | (q >> 1)) ^ ((arow >> 1) & 3)) << 4) + ((q & 1) << 3));
            }
#pragma unroll
            for (int j = 0; j < 4; j++) {
                int brow = wn + j * 16 + r;
                bf[j] = *(const long*)(Bs + brow * 64 +
                        ((((ks << 1) | (q >> 1)) ^ ((brow >> 1) & 3)) << 4) + ((q & 1) << 3));
            }
#pragma unroll
            for (int i = 0; i < 4; i++)
#pragma unroll
                for (int j = 0; j < 4; j++)
                    acc[i][j] = __builtin_amdgcn_mfma_f32_16x16x32_fp8_fp8(af[i], bf[j],
                                                                           acc[i][j], 0, 0, 0);
        }
        __syncthreads();
    }

    // epilogue: D[m][n], m = wm + i*16 + q*4 + rr, n = wn + j*16 + r
    const float wsc = fmaxf(__uint_as_float(*wmaxbits) / FP8MAX, 1e-12f);
#pragma unroll
    for (int i = 0; i < 4; i++) {
#pragma unroll
        for (int rr = 0; rr < 4; rr++) {
            const int m = m0 + wm + i * 16 + q * 4 + rr;
            const float sv = srow[m] * wsc;
            float* orow = out + (size_t)m * HD + n0 + wn + r;
#pragma unroll
            for (int j = 0; j < 4; j++)
                orow[j * 16] = acc[i][j][rr] * sv;
        }
    }
}

// ---------------- launch ----------------
extern "C" void kernel_launch(void* const* d_in, const int* in_sizes, int n_in,
                              void* d_out, int out_size, void* d_ws, size_t ws_size,
                              hipStream_t stream) {
    const float* x   = (const float*)d_in[0];
    const float* nw0 = (const float*)d_in[1];
    const float* nw1 = (const float*)d_in[2];
    const float* nw2 = (const float*)d_in[3];
    const float* nw3 = (const float*)d_in[4];
    const float* W0  = (const float*)d_in[5];
    const float* W1  = (const float*)d_in[6];
    const float* W2  = (const float*)d_in[7];
    float* out = (float*)d_out;

    char* ws = (char*)d_ws;
    // workspace layout (x2 buffer lives in d_out to save space)
    float*    resid = (float*)(ws);                                  // 64 MiB
    uint32_t* qx    = (uint32_t*)(ws + (size_t)67108864);            // 16 MiB
    uint32_t* qw    = (uint32_t*)(ws + (size_t)83886080);            // 16 MiB
    float*    srow  = (float*)(ws + (size_t)100663296);              // 16 KiB
    uint32_t* wmax  = (uint32_t*)(ws + (size_t)100679680);           // 12 B
    float*    x2    = out;                                           // reuse d_out

    hipMemsetAsync(wmax, 0, 12, stream);
    hipLaunchKernelGGL(w_absmax, dim3(1024, 1, 3), dim3(256), 0, stream, W0, W1, W2, wmax);

    // layer 0 input: relu(x) -> resid, rmsnorm+quant
    hipLaunchKernelGGL(fused_rms, dim3(4096), dim3(256), 0, stream,
                       x, (const float*)nullptr, resid, nw0, qx, srow, (float*)nullptr, 0);

    const float* Ws[3]  = {W0, W1, W2};
    const float* nws[3] = {nw1, nw2, nw3};
    for (int l = 0; l < 3; l++) {
        hipLaunchKernelGGL(w_quant, dim3(HD * HD / 4 / 256), dim3(256), 0, stream,
                           Ws[l], wmax + l, qw);
        hipLaunchKernelGGL(gemm_fp8, dim3(32, 32), dim3(256), 0, stream,
                           (const uint8_t*)qx, (const uint8_t*)qw, srow, wmax + l, x2);
        if (l < 2) {
            hipLaunchKernelGGL(fused_rms, dim3(4096), dim3(256), 0, stream,
                               x2, (const float*)resid, resid, nws[l], qx, srow,
                               (float*)nullptr, 1);
        } else {
            hipLaunchKernelGGL(fused_rms, dim3(4096), dim3(256), 0, stream,
                               x2, (const float*)resid, (float*)nullptr, nws[l],
                               (uint32_t*)nullptr, (float*)nullptr, out, 2);
        }
    }
}

// Round 2
// 657.331 us; speedup vs baseline: 1.1983x; 1.1983x over previous
//
#include <hip/hip_runtime.h>
#include <cstdint>
#include <cstddef>

#define AS1 __attribute__((address_space(1)))
#define AS3 __attribute__((address_space(3)))

typedef __attribute__((ext_vector_type(4))) float f32x4;
typedef __attribute__((ext_vector_type(16))) float f32x16;
typedef __attribute__((ext_vector_type(4))) int i32x4;
typedef __attribute__((ext_vector_type(8))) int i32x8;

constexpr int HD = 4096;   // hidden dim (= K = out dim)
constexpr float FP8MAX = 448.0f;

// ---------------- reductions ----------------
__device__ inline float wave_red(float v, bool ismax) {
#pragma unroll
    for (int i = 32; i > 0; i >>= 1) {
        float o = __shfl_xor(v, i, 64);
        v = ismax ? fmaxf(v, o) : (v + o);
    }
    return v;
}

__device__ inline float blk_red(float v, float* red, bool ismax) {
    v = wave_red(v, ismax);
    const int wid = threadIdx.x >> 6;
    __syncthreads();                      // protect red from previous use
    if ((threadIdx.x & 63) == 0) red[wid] = v;
    __syncthreads();
    float a = red[0], b = red[1], c = red[2], d = red[3];
    return ismax ? fmaxf(fmaxf(a, b), fmaxf(c, d)) : ((a + b) + (c + d));
}

// ---------------- fp8 pack ----------------
__device__ inline uint32_t pack4_fp8(float a, float b, float c, float d) {
    int v = 0;
    v = __builtin_amdgcn_cvt_pk_fp8_f32(a, b, v, false);  // low word
    v = __builtin_amdgcn_cvt_pk_fp8_f32(c, d, v, true);   // high word
    return (uint32_t)v;
}

__device__ inline float clipdiv(float y, float s) {
    float t = y / s;                       // IEEE div to match numpy exactly
    t = fminf(t, FP8MAX);
    t = fmaxf(t, -FP8MAX);
    return t;
}

// ---------------- weight absmax (per tensor, blockIdx.z selects W) ----------------
__global__ __launch_bounds__(256) void w_absmax(const float* __restrict__ W0,
                                                const float* __restrict__ W1,
                                                const float* __restrict__ W2,
                                                uint32_t* __restrict__ wmax) {
    __shared__ float red[4];
    const float* W = (blockIdx.z == 0) ? W0 : (blockIdx.z == 1 ? W1 : W2);
    const float4* W4 = (const float4*)W;
    const int n4 = HD * HD / 4;
    float m = 0.f;
    for (int i = blockIdx.x * blockDim.x + threadIdx.x; i < n4; i += gridDim.x * blockDim.x) {
        float4 v = W4[i];
        m = fmaxf(m, fmaxf(fmaxf(fabsf(v.x), fabsf(v.y)), fmaxf(fabsf(v.z), fabsf(v.w))));
    }
    m = blk_red(m, red, true);
    if (threadIdx.x == 0)
        atomicMax((unsigned int*)(wmax + blockIdx.z), __float_as_uint(m));
}

// ---------------- weight quantize ----------------
__global__ __launch_bounds__(256) void w_quant(const float* __restrict__ W,
                                               const uint32_t* __restrict__ wmaxbits,
                                               uint32_t* __restrict__ qw) {
    const float sw = fmaxf(__uint_as_float(*wmaxbits) / FP8MAX, 1e-12f);
    const int i = blockIdx.x * blockDim.x + threadIdx.x;
    float4 v = ((const float4*)W)[i];
    qw[i] = pack4_fp8(clipdiv(v.x, sw), clipdiv(v.y, sw), clipdiv(v.z, sw), clipdiv(v.w, sw));
}

// ---------------- fused (relu|add) + rmsnorm + (quant | final write) ----------------
// mode 0: v = relu(xin); store resid; quant
// mode 1: v = xin + addin; store resid; quant
// mode 2: v = xin + addin; write y to yout (final), no resid/quant
__global__ __launch_bounds__(256) void fused_rms(const float* __restrict__ xin,
                                                 const float* __restrict__ addin,
                                                 float* __restrict__ resid_out,
                                                 const float* __restrict__ nw,
                                                 uint32_t* __restrict__ qx,
                                                 float* __restrict__ srow,
                                                 float* __restrict__ yout,
                                                 const int mode) {
    __shared__ float red[4];
    const int row = blockIdx.x;
    const int tid = threadIdx.x;
    const size_t base = (size_t)row * HD;
    const float4* xr = (const float4*)(xin + base);

    float4 v[4];
    float ss = 0.f;
    if (mode == 0) {
#pragma unroll
        for (int j = 0; j < 4; j++) {
            float4 t = xr[tid + j * 256];
            t.x = fmaxf(t.x, 0.f); t.y = fmaxf(t.y, 0.f);
            t.z = fmaxf(t.z, 0.f); t.w = fmaxf(t.w, 0.f);
            v[j] = t;
            ss += t.x * t.x + t.y * t.y + t.z * t.z + t.w * t.w;
        }
    } else {
        const float4* ar = (const float4*)(addin + base);
#pragma unroll
        for (int j = 0; j < 4; j++) {
            float4 t = xr[tid + j * 256];
            float4 a = ar[tid + j * 256];
            t.x += a.x; t.y += a.y; t.z += a.z; t.w += a.w;
            v[j] = t;
            ss += t.x * t.x + t.y * t.y + t.z * t.z + t.w * t.w;
        }
    }
    if (resid_out) {
        float4* ro = (float4*)(resid_out + base);
#pragma unroll
        for (int j = 0; j < 4; j++) ro[tid + j * 256] = v[j];
    }
    ss = blk_red(ss, red, false);
    const float rs = 1.0f / sqrtf(ss / (float)HD + 1e-6f);

    const float4* nw4 = (const float4*)nw;
    float4 y[4];
    float amax = 0.f;
#pragma unroll
    for (int j = 0; j < 4; j++) {
        float4 w = nw4[tid + j * 256];
        float4 t;
        t.x = (v[j].x * rs) * w.x; t.y = (v[j].y * rs) * w.y;
        t.z = (v[j].z * rs) * w.z; t.w = (v[j].w * rs) * w.w;
        y[j] = t;
        amax = fmaxf(amax, fmaxf(fmaxf(fabsf(t.x), fabsf(t.y)), fmaxf(fabsf(t.z), fabsf(t.w))));
    }

    if (mode == 2) {
        float4* yo = (float4*)(yout + base);
#pragma unroll
        for (int j = 0; j < 4; j++) yo[tid + j * 256] = y[j];
        return;
    }

    amax = blk_red(amax, red, true);
    const float s = fmaxf(amax / FP8MAX, 1e-12f);
    if (tid == 0) srow[row] = s;
    uint32_t* qr = qx + base / 4;
#pragma unroll
    for (int j = 0; j < 4; j++) {
        qr[tid + j * 256] = pack4_fp8(clipdiv(y[j].x, s), clipdiv(y[j].y, s),
                                      clipdiv(y[j].z, s), clipdiv(y[j].w, s));
    }
}

// ---------------- MX-scaled fp8 GEMM ----------------
// out[m][n] = (sum_k qx[m][k]*qw[n][k]) * srow[m] * ws
// 128x128 tile, BK=128, 4 waves in 2x2, each wave 2x2 tiles of 32x32x64
// mfma_scale_f32_32x32x64_f8f6f4 with fp8 format and scale=1.0 (E8M0 127):
// numerically identical to non-scaled fp8 MFMA, 2x the rate.
// LDS rows are 128 B = 8 16B-groups, XOR-swizzled: physical group = logical ^ (row&7).
// Fragment ds_read_b128s then hit exactly 8 accesses/bank (the wave64 minimum).
__global__ __launch_bounds__(256) void gemm_fp8mx(const uint8_t* __restrict__ qx,
                                                  const uint8_t* __restrict__ qw,
                                                  const float* __restrict__ srow,
                                                  const uint32_t* __restrict__ wmaxbits,
                                                  float* __restrict__ out) {
    __shared__ uint8_t As[128 * 128];
    __shared__ uint8_t Bs[128 * 128];

    const int tid = threadIdx.x;
    const int wave = tid >> 6;
    const int lane = tid & 63;
    const int lr = lane & 31;   // row within a 32-tile (A/B operand row)
    const int lh = lane >> 5;   // k-half selector

    const int m0 = blockIdx.y * 128;
    const int n0 = blockIdx.x * 128;
    const int wm = (wave >> 1) * 64;
    const int wn = (wave & 1) * 64;

    f32x16 acc[2][2];
#pragma unroll
    for (int i = 0; i < 2; i++)
#pragma unroll
        for (int j = 0; j < 2; j++)
#pragma unroll
            for (int e = 0; e < 16; e++) acc[i][j][e] = 0.f;

    // staging: physical slot = c*4096 + wave*1024 + lane*16 (wave-uniform base + lane*16).
    // slot row = c*32 + wave*8 + (lane>>3), physical group = lane&7.
    // source logical group = (lane&7) ^ (row&7) = (lane&7) ^ (lane>>3).
    const int strow = wave * 8 + (lane >> 3);
    const int sg = (lane & 7) ^ (lane >> 3);
    const uint8_t* aga = qx + (size_t)(m0 + strow) * HD + sg * 16;
    const uint8_t* bga = qw + (size_t)(n0 + strow) * HD + sg * 16;
    const int ldst = wave * 1024 + lane * 16;

    for (int k0 = 0; k0 < HD; k0 += 128) {
#pragma unroll
        for (int c = 0; c < 4; c++) {
            __builtin_amdgcn_global_load_lds((const AS1 void*)(aga + (size_t)c * 32 * HD + k0),
                                             (AS3 void*)(As + c * 4096 + ldst), 16, 0, 0);
            __builtin_amdgcn_global_load_lds((const AS1 void*)(bga + (size_t)c * 32 * HD + k0),
                                             (AS3 void*)(Bs + c * 4096 + ldst), 16, 0, 0);
        }
        __syncthreads();

#pragma unroll
        for (int kh = 0; kh < 2; kh++) {
            union { i32x8 v8; i32x4 v4[2]; } af[2], bf[2];
            const int kg0 = kh * 4 + lh * 2;      // logical 16B group of this lane's k-chunk
#pragma unroll
            for (int i = 0; i < 2; i++) {
                const int ar = wm + i * 32 + lr;          // ar&7 == lane&7
                const uint8_t* pa = As + ar * 128;
                af[i].v4[0] = *(const i32x4*)(pa + ((kg0 ^ (ar & 7)) << 4));
                af[i].v4[1] = *(const i32x4*)(pa + (((kg0 + 1) ^ (ar & 7)) << 4));
                const int br = wn + i * 32 + lr;
                const uint8_t* pb = Bs + br * 128;
                bf[i].v4[0] = *(const i32x4*)(pb + ((kg0 ^ (br & 7)) << 4));
                bf[i].v4[1] = *(const i32x4*)(pb + (((kg0 + 1) ^ (br & 7)) << 4));
            }
#pragma unroll
            for (int i = 0; i < 2; i++)
#pragma unroll
                for (int j = 0; j < 2; j++)
                    acc[i][j] = __builtin_amdgcn_mfma_scale_f32_32x32x64_f8f6f4(
                        af[i].v8, bf[j].v8, acc[i][j],
                        0, 0,                       // cbsz=fp8, blgp=fp8
                        0, 0x7F7F7F7Fu,             // A scale opsel, E8M0 127 = 1.0
                        0, 0x7F7F7F7Fu);            // B scale
        }
        __syncthreads();
    }

    // epilogue: D 32x32 tile: col = lane&31, row = (reg&3) + 8*(reg>>2) + 4*(lane>>5)
    const float wsc = fmaxf(__uint_as_float(*wmaxbits) / FP8MAX, 1e-12f);
#pragma unroll
    for (int i = 0; i < 2; i++) {
#pragma unroll
        for (int reg = 0; reg < 16; reg++) {
            const int row = (reg & 3) + 8 * (reg >> 2) + 4 * lh;
            const int m = m0 + wm + i * 32 + row;
            const float sv = srow[m] * wsc;
            float* orow = out + (size_t)m * HD + n0 + wn + lr;
#pragma unroll
            for (int j = 0; j < 2; j++)
                orow[j * 32] = acc[i][j][reg] * sv;
        }
    }
}

// ---------------- launch ----------------
extern "C" void kernel_launch(void* const* d_in, const int* in_sizes, int n_in,
                              void* d_out, int out_size, void* d_ws, size_t ws_size,
                              hipStream_t stream) {
    const float* x   = (const float*)d_in[0];
    const float* nw0 = (const float*)d_in[1];
    const float* nw1 = (const float*)d_in[2];
    const float* nw2 = (const float*)d_in[3];
    const float* nw3 = (const float*)d_in[4];
    const float* W0  = (const float*)d_in[5];
    const float* W1  = (const float*)d_in[6];
    const float* W2  = (const float*)d_in[7];
    float* out = (float*)d_out;

    char* ws = (char*)d_ws;
    // workspace layout (x2 buffer lives in d_out to save space)
    float*    resid = (float*)(ws);                                  // 64 MiB
    uint32_t* qx    = (uint32_t*)(ws + (size_t)67108864);            // 16 MiB
    uint32_t* qw    = (uint32_t*)(ws + (size_t)83886080);            // 16 MiB
    float*    srow  = (float*)(ws + (size_t)100663296);              // 16 KiB
    uint32_t* wmax  = (uint32_t*)(ws + (size_t)100679680);           // 12 B
    float*    x2    = out;                                           // reuse d_out

    hipMemsetAsync(wmax, 0, 12, stream);
    hipLaunchKernelGGL(w_absmax, dim3(1024, 1, 3), dim3(256), 0, stream, W0, W1, W2, wmax);

    // layer 0 input: relu(x) -> resid, rmsnorm+quant
    hipLaunchKernelGGL(fused_rms, dim3(4096), dim3(256), 0, stream,
                       x, (const float*)nullptr, resid, nw0, qx, srow, (float*)nullptr, 0);

    const float* Ws[3]  = {W0, W1, W2};
    const float* nws[3] = {nw1, nw2, nw3};
    for (int l = 0; l < 3; l++) {
        hipLaunchKernelGGL(w_quant, dim3(HD * HD / 4 / 256), dim3(256), 0, stream,
                           Ws[l], wmax + l, qw);
        hipLaunchKernelGGL(gemm_fp8mx, dim3(32, 32), dim3(256), 0, stream,
                           (const uint8_t*)qx, (const uint8_t*)qw, srow, wmax + l, x2);
        if (l < 2) {
            hipLaunchKernelGGL(fused_rms, dim3(4096), dim3(256), 0, stream,
                               x2, (const float*)resid, resid, nws[l], qx, srow,
                               (float*)nullptr, 1);
        } else {
            hipLaunchKernelGGL(fused_rms, dim3(4096), dim3(256), 0, stream,
                               x2, (const float*)resid, (float*)nullptr, nws[l],
                               (uint32_t*)nullptr, (float*)nullptr, out, 2);
        }
    }
}

// Round 3
// 647.789 us; speedup vs baseline: 1.2159x; 1.0147x over previous
//
#include <hip/hip_runtime.h>
#include <cstdint>
#include <cstddef>

#define AS1 __attribute__((address_space(1)))
#define AS3 __attribute__((address_space(3)))

typedef __attribute__((ext_vector_type(4))) float f32x4;
typedef __attribute__((ext_vector_type(16))) float f32x16;
typedef __attribute__((ext_vector_type(4))) int i32x4;
typedef __attribute__((ext_vector_type(8))) int i32x8;

constexpr int HD = 4096;   // hidden dim (= K = out dim)
constexpr float FP8MAX = 448.0f;

// ---------------- fp8 pack ----------------
__device__ inline uint32_t pack4_fp8(float a, float b, float c, float d) {
    int v = 0;
    v = __builtin_amdgcn_cvt_pk_fp8_f32(a, b, v, false);  // low word
    v = __builtin_amdgcn_cvt_pk_fp8_f32(c, d, v, true);   // high word
    return (uint32_t)v;
}

__device__ inline float clipmul(float y, float rcs) {
    float t = y * rcs;                     // rcs = 1/s (one IEEE div upstream)
    t = fminf(t, FP8MAX);
    t = fmaxf(t, -FP8MAX);
    return t;
}

__device__ inline uint32_t quant4(float4 v, float rcs) {
    return pack4_fp8(clipmul(v.x, rcs), clipmul(v.y, rcs),
                     clipmul(v.z, rcs), clipmul(v.w, rcs));
}

// ---------------- weight absmax (per tensor, blockIdx.z selects W) ----------------
__global__ __launch_bounds__(256) void w_absmax(const float* __restrict__ W0,
                                                const float* __restrict__ W1,
                                                const float* __restrict__ W2,
                                                uint32_t* __restrict__ wmax) {
    __shared__ float red[4];
    const float* W = (blockIdx.z == 0) ? W0 : (blockIdx.z == 1 ? W1 : W2);
    const float4* W4 = (const float4*)W;
    const int n4 = HD * HD / 4;
    float m = 0.f;
    for (int i = blockIdx.x * blockDim.x + threadIdx.x; i < n4; i += gridDim.x * blockDim.x) {
        float4 v = W4[i];
        m = fmaxf(m, fmaxf(fmaxf(fabsf(v.x), fabsf(v.y)), fmaxf(fabsf(v.z), fabsf(v.w))));
    }
#pragma unroll
    for (int i = 32; i > 0; i >>= 1) m = fmaxf(m, __shfl_xor(m, i, 64));
    if ((threadIdx.x & 63) == 0) red[threadIdx.x >> 6] = m;
    __syncthreads();
    if (threadIdx.x == 0) {
        m = fmaxf(fmaxf(red[0], red[1]), fmaxf(red[2], red[3]));
        atomicMax((unsigned int*)(wmax + blockIdx.z), __float_as_uint(m));
    }
}

// ---------------- standalone weight quantize (fallback path only) ----------------
__global__ __launch_bounds__(256) void w_quant(const float* __restrict__ W,
                                               const uint32_t* __restrict__ wmaxbits,
                                               uint32_t* __restrict__ qw) {
    const float rsw = 1.0f / fmaxf(__uint_as_float(*wmaxbits) / FP8MAX, 1e-12f);
    const int i = blockIdx.x * blockDim.x + threadIdx.x;
    qw[i] = quant4(((const float4*)W)[i], rsw);
}

// ---------------- fused (relu|add) + rmsnorm + (quant | final write) [+ W quant] ----------------
// Blocks [0,4096): row work.  Blocks [4096, 8192) (when launched): quantize Wq -> qwout.
// mode 0: v = relu(xin); store resid; quant
// mode 1: v = xin + addin; store resid; quant
// mode 2: v = xin + addin; write y to yout (final), no resid/quant
// Single combined block reduction: sum(v*v) and max|v*w| ride the same barrier;
// amax = rs * max|v*w| (differs from ref max|v*rs*w| by ~1 ulp of s -> negligible).
__global__ __launch_bounds__(256) void fused_rms(const float* __restrict__ xin,
                                                 const float* __restrict__ addin,
                                                 float* __restrict__ resid_out,
                                                 const float* __restrict__ nw,
                                                 uint32_t* __restrict__ qx,
                                                 float* __restrict__ srow,
                                                 float* __restrict__ yout,
                                                 const int mode,
                                                 const float* __restrict__ Wq,
                                                 const uint32_t* __restrict__ wqmaxbits,
                                                 uint32_t* __restrict__ qwout) {
    const int tid = threadIdx.x;
    if (blockIdx.x >= 4096) {
        // ---- merged weight-quant blocks ----
        const float rsw = 1.0f / fmaxf(__uint_as_float(*wqmaxbits) / FP8MAX, 1e-12f);
        const float4* W4 = (const float4*)Wq;
        int i = (blockIdx.x - 4096) * 256 + tid;
#pragma unroll
        for (int it = 0; it < 4; it++, i += 4096 * 256)
            qwout[i] = quant4(W4[i], rsw);
        return;
    }

    __shared__ float reds[4];
    __shared__ float redm[4];
    const int row = blockIdx.x;
    const size_t base = (size_t)row * HD;
    const float4* xr = (const float4*)(xin + base);
    const float4* nw4 = (const float4*)nw;

    float4 v[4], w[4];
    float ss = 0.f, pm = 0.f;
    if (mode == 0) {
#pragma unroll
        for (int j = 0; j < 4; j++) {
            float4 t = xr[tid + j * 256];
            w[j] = nw4[tid + j * 256];
            t.x = fmaxf(t.x, 0.f); t.y = fmaxf(t.y, 0.f);
            t.z = fmaxf(t.z, 0.f); t.w = fmaxf(t.w, 0.f);
            v[j] = t;
            ss += t.x * t.x + t.y * t.y + t.z * t.z + t.w * t.w;
            pm = fmaxf(pm, fmaxf(fmaxf(fabsf(t.x * w[j].x), fabsf(t.y * w[j].y)),
                                 fmaxf(fabsf(t.z * w[j].z), fabsf(t.w * w[j].w))));
        }
    } else {
        const float4* ar = (const float4*)(addin + base);
#pragma unroll
        for (int j = 0; j < 4; j++) {
            float4 t = xr[tid + j * 256];
            float4 a = ar[tid + j * 256];
            w[j] = nw4[tid + j * 256];
            t.x += a.x; t.y += a.y; t.z += a.z; t.w += a.w;
            v[j] = t;
            ss += t.x * t.x + t.y * t.y + t.z * t.z + t.w * t.w;
            pm = fmaxf(pm, fmaxf(fmaxf(fabsf(t.x * w[j].x), fabsf(t.y * w[j].y)),
                                 fmaxf(fabsf(t.z * w[j].z), fabsf(t.w * w[j].w))));
        }
    }
    if (resid_out) {
        float4* ro = (float4*)(resid_out + base);
#pragma unroll
        for (int j = 0; j < 4; j++) ro[tid + j * 256] = v[j];
    }

    // combined block reduction (one barrier phase)
#pragma unroll
    for (int i = 32; i > 0; i >>= 1) {
        ss += __shfl_xor(ss, i, 64);
        pm = fmaxf(pm, __shfl_xor(pm, i, 64));
    }
    if ((tid & 63) == 0) { reds[tid >> 6] = ss; redm[tid >> 6] = pm; }
    __syncthreads();
    ss = (reds[0] + reds[1]) + (reds[2] + reds[3]);
    pm = fmaxf(fmaxf(redm[0], redm[1]), fmaxf(redm[2], redm[3]));

    const float rs = 1.0f / sqrtf(ss / (float)HD + 1e-6f);

    if (mode == 2) {
        float4* yo = (float4*)(yout + base);
#pragma unroll
        for (int j = 0; j < 4; j++) {
            float4 t;
            t.x = (v[j].x * rs) * w[j].x; t.y = (v[j].y * rs) * w[j].y;
            t.z = (v[j].z * rs) * w[j].z; t.w = (v[j].w * rs) * w[j].w;
            yo[tid + j * 256] = t;
        }
        return;
    }

    const float amax = pm * rs;
    const float s = fmaxf(amax / FP8MAX, 1e-12f);
    const float rcs = 1.0f / s;
    if (tid == 0) srow[row] = s;
    uint32_t* qr = qx + base / 4;
#pragma unroll
    for (int j = 0; j < 4; j++) {
        float4 t;
        t.x = (v[j].x * rs) * w[j].x; t.y = (v[j].y * rs) * w[j].y;
        t.z = (v[j].z * rs) * w[j].z; t.w = (v[j].w * rs) * w[j].w;
        qr[tid + j * 256] = quant4(t, rcs);
    }
}

// ---------------- MX-scaled fp8 GEMM (+ merged next-layer weight quant) ----------------
// blockIdx.z==0: out[m][n] = (sum_k qx[m][k]*qw[n][k]) * srow[m] * ws
//   128x128 tile, BK=128, 4 waves in 2x2, each wave 2x2 tiles of 32x32x64
//   mfma_scale with E8M0 scale 127 (=1.0): numerically identical to plain fp8 MFMA.
//   LDS rows 128 B = 8 groups, XOR-swizzled (physical = logical ^ (row&7)) -> conflict-min.
// blockIdx.z==1: quantize Wnext -> qwnext (independent data; hides under the GEMM).
__global__ __launch_bounds__(256) void gemm_fp8mx(const uint8_t* __restrict__ qx,
                                                  const uint8_t* __restrict__ qw,
                                                  const float* __restrict__ srow,
                                                  const uint32_t* __restrict__ wmaxbits,
                                                  float* __restrict__ out,
                                                  const float* __restrict__ Wnext,
                                                  const uint32_t* __restrict__ wnmaxbits,
                                                  uint32_t* __restrict__ qwnext) {
    __shared__ uint8_t As[128 * 128];
    __shared__ uint8_t Bs[128 * 128];

    const int tid = threadIdx.x;

    if (blockIdx.z == 1) {
        const float rsw = 1.0f / fmaxf(__uint_as_float(*wnmaxbits) / FP8MAX, 1e-12f);
        const float4* W4 = (const float4*)Wnext;
        int i = (blockIdx.y * 32 + blockIdx.x) * 256 + tid;
#pragma unroll
        for (int it = 0; it < 16; it++, i += 1024 * 256)
            qwnext[i] = quant4(W4[i], rsw);
        return;
    }

    const int wave = tid >> 6;
    const int lane = tid & 63;
    const int lr = lane & 31;   // row within a 32-tile (A/B operand row)
    const int lh = lane >> 5;   // k-half selector

    const int m0 = blockIdx.y * 128;
    const int n0 = blockIdx.x * 128;
    const int wm = (wave >> 1) * 64;
    const int wn = (wave & 1) * 64;

    f32x16 acc[2][2];
#pragma unroll
    for (int i = 0; i < 2; i++)
#pragma unroll
        for (int j = 0; j < 2; j++)
#pragma unroll
            for (int e = 0; e < 16; e++) acc[i][j][e] = 0.f;

    // staging: physical slot = c*4096 + wave*1024 + lane*16 (wave-uniform base + lane*16).
    // slot row = c*32 + wave*8 + (lane>>3), physical group = lane&7.
    // source logical group = (lane&7) ^ (row&7) = (lane&7) ^ (lane>>3).
    const int strow = wave * 8 + (lane >> 3);
    const int sg = (lane & 7) ^ (lane >> 3);
    const uint8_t* aga = qx + (size_t)(m0 + strow) * HD + sg * 16;
    const uint8_t* bga = qw + (size_t)(n0 + strow) * HD + sg * 16;
    const int ldst = wave * 1024 + lane * 16;

    for (int k0 = 0; k0 < HD; k0 += 128) {
#pragma unroll
        for (int c = 0; c < 4; c++) {
            __builtin_amdgcn_global_load_lds((const AS1 void*)(aga + (size_t)c * 32 * HD + k0),
                                             (AS3 void*)(As + c * 4096 + ldst), 16, 0, 0);
            __builtin_amdgcn_global_load_lds((const AS1 void*)(bga + (size_t)c * 32 * HD + k0),
                                             (AS3 void*)(Bs + c * 4096 + ldst), 16, 0, 0);
        }
        __syncthreads();

#pragma unroll
        for (int kh = 0; kh < 2; kh++) {
            union { i32x8 v8; i32x4 v4[2]; } af[2], bf[2];
            const int kg0 = kh * 4 + lh * 2;      // logical 16B group of this lane's k-chunk
#pragma unroll
            for (int i = 0; i < 2; i++) {
                const int ar = wm + i * 32 + lr;
                const uint8_t* pa = As + ar * 128;
                af[i].v4[0] = *(const i32x4*)(pa + ((kg0 ^ (ar & 7)) << 4));
                af[i].v4[1] = *(const i32x4*)(pa + (((kg0 + 1) ^ (ar & 7)) << 4));
                const int br = wn + i * 32 + lr;
                const uint8_t* pb = Bs + br * 128;
                bf[i].v4[0] = *(const i32x4*)(pb + ((kg0 ^ (br & 7)) << 4));
                bf[i].v4[1] = *(const i32x4*)(pb + (((kg0 + 1) ^ (br & 7)) << 4));
            }
#pragma unroll
            for (int i = 0; i < 2; i++)
#pragma unroll
                for (int j = 0; j < 2; j++)
                    acc[i][j] = __builtin_amdgcn_mfma_scale_f32_32x32x64_f8f6f4(
                        af[i].v8, bf[j].v8, acc[i][j],
                        0, 0,                       // cbsz=fp8, blgp=fp8
                        0, 0x7F7F7F7Fu,             // A scale, E8M0 127 = 1.0
                        0, 0x7F7F7F7Fu);            // B scale
        }
        __syncthreads();
    }

    // epilogue: D 32x32 tile: col = lane&31, row = (reg&3) + 8*(reg>>2) + 4*(lane>>5)
    const float wsc = fmaxf(__uint_as_float(*wmaxbits) / FP8MAX, 1e-12f);
#pragma unroll
    for (int i = 0; i < 2; i++) {
#pragma unroll
        for (int reg = 0; reg < 16; reg++) {
            const int row = (reg & 3) + 8 * (reg >> 2) + 4 * lh;
            const int m = m0 + wm + i * 32 + row;
            const float sv = srow[m] * wsc;
            float* orow = out + (size_t)m * HD + n0 + wn + lr;
#pragma unroll
            for (int j = 0; j < 2; j++)
                orow[j * 32] = acc[i][j][reg] * sv;
        }
    }
}

// ---------------- launch ----------------
extern "C" void kernel_launch(void* const* d_in, const int* in_sizes, int n_in,
                              void* d_out, int out_size, void* d_ws, size_t ws_size,
                              hipStream_t stream) {
    const float* x   = (const float*)d_in[0];
    const float* nw0 = (const float*)d_in[1];
    const float* nw1 = (const float*)d_in[2];
    const float* nw2 = (const float*)d_in[3];
    const float* nw3 = (const float*)d_in[4];
    const float* W0  = (const float*)d_in[5];
    const float* W1  = (const float*)d_in[6];
    const float* W2  = (const float*)d_in[7];
    float* out = (float*)d_out;

    char* ws = (char*)d_ws;
    const size_t MB = 1024 * 1024;
    float* x2 = out;                       // x2 buffer lives in d_out

    const bool overlap = ws_size >= 118 * MB;

    if (overlap) {
        float*    resid = (float*)(ws);                    // 64 MiB
        uint32_t* qx    = (uint32_t*)(ws + 64 * MB);       // 16 MiB
        uint32_t* qwA   = (uint32_t*)(ws + 80 * MB);       // 16 MiB
        uint32_t* qwB   = (uint32_t*)(ws + 96 * MB);       // 16 MiB
        float*    srow  = (float*)(ws + 112 * MB);         // 16 KiB
        uint32_t* wmax  = (uint32_t*)(ws + 112 * MB + 16384);

        hipMemsetAsync(wmax, 0, 12, stream);
        hipLaunchKernelGGL(w_absmax, dim3(1024, 1, 3), dim3(256), 0, stream, W0, W1, W2, wmax);

        // relu+rms+quant rows, merged with W0 quantization
        hipLaunchKernelGGL(fused_rms, dim3(8192), dim3(256), 0, stream,
                           x, (const float*)nullptr, resid, nw0, qx, srow, (float*)nullptr, 0,
                           W0, wmax + 0, qwA);
        // gemm0 (qwA), merged with W1 quantization -> qwB
        hipLaunchKernelGGL(gemm_fp8mx, dim3(32, 32, 2), dim3(256), 0, stream,
                           (const uint8_t*)qx, (const uint8_t*)qwA, srow, wmax + 0, x2,
                           W1, wmax + 1, qwB);
        hipLaunchKernelGGL(fused_rms, dim3(4096), dim3(256), 0, stream,
                           x2, (const float*)resid, resid, nw1, qx, srow, (float*)nullptr, 1,
                           (const float*)nullptr, (const uint32_t*)nullptr, (uint32_t*)nullptr);
        // gemm1 (qwB), merged with W2 quantization -> qwA
        hipLaunchKernelGGL(gemm_fp8mx, dim3(32, 32, 2), dim3(256), 0, stream,
                           (const uint8_t*)qx, (const uint8_t*)qwB, srow, wmax + 1, x2,
                           W2, wmax + 2, qwA);
        hipLaunchKernelGGL(fused_rms, dim3(4096), dim3(256), 0, stream,
                           x2, (const float*)resid, resid, nw2, qx, srow, (float*)nullptr, 1,
                           (const float*)nullptr, (const uint32_t*)nullptr, (uint32_t*)nullptr);
        // gemm2 (qwA), no merged quant
        hipLaunchKernelGGL(gemm_fp8mx, dim3(32, 32, 1), dim3(256), 0, stream,
                           (const uint8_t*)qx, (const uint8_t*)qwA, srow, wmax + 2, x2,
                           (const float*)nullptr, (const uint32_t*)nullptr, (uint32_t*)nullptr);
        hipLaunchKernelGGL(fused_rms, dim3(4096), dim3(256), 0, stream,
                           x2, (const float*)resid, (float*)nullptr, nw3,
                           (uint32_t*)nullptr, (float*)nullptr, out, 2,
                           (const float*)nullptr, (const uint32_t*)nullptr, (uint32_t*)nullptr);
    } else {
        // sequential fallback (round-2 structure, single qw buffer)
        float*    resid = (float*)(ws);
        uint32_t* qx    = (uint32_t*)(ws + 64 * MB);
        uint32_t* qw    = (uint32_t*)(ws + 80 * MB);
        float*    srow  = (float*)(ws + 96 * MB);
        uint32_t* wmax  = (uint32_t*)(ws + 96 * MB + 16384);

        hipMemsetAsync(wmax, 0, 12, stream);
        hipLaunchKernelGGL(w_absmax, dim3(1024, 1, 3), dim3(256), 0, stream, W0, W1, W2, wmax);
        hipLaunchKernelGGL(fused_rms, dim3(4096), dim3(256), 0, stream,
                           x, (const float*)nullptr, resid, nw0, qx, srow, (float*)nullptr, 0,
                           (const float*)nullptr, (const uint32_t*)nullptr, (uint32_t*)nullptr);
        const float* Ws[3]  = {W0, W1, W2};
        const float* nws[3] = {nw1, nw2, nw3};
        for (int l = 0; l < 3; l++) {
            hipLaunchKernelGGL(w_quant, dim3(HD * HD / 4 / 256), dim3(256), 0, stream,
                               Ws[l], wmax + l, qw);
            hipLaunchKernelGGL(gemm_fp8mx, dim3(32, 32, 1), dim3(256), 0, stream,
                               (const uint8_t*)qx, (const uint8_t*)qw, srow, wmax + l, x2,
                               (const float*)nullptr, (const uint32_t*)nullptr, (uint32_t*)nullptr);
            if (l < 2) {
                hipLaunchKernelGGL(fused_rms, dim3(4096), dim3(256), 0, stream,
                                   x2, (const float*)resid, resid, nws[l], qx, srow,
                                   (float*)nullptr, 1,
                                   (const float*)nullptr, (const uint32_t*)nullptr, (uint32_t*)nullptr);
            } else {
                hipLaunchKernelGGL(fused_rms, dim3(4096), dim3(256), 0, stream,
                                   x2, (const float*)resid, (float*)nullptr, nws[l],
                                   (uint32_t*)nullptr, (float*)nullptr, out, 2,
                                   (const float*)nullptr, (const uint32_t*)nullptr, (uint32_t*)nullptr);
            }
        }
    }
}